// Round 1
// baseline (147.439 us; speedup 1.0000x reference)
//
#include <hip/hip_runtime.h>

#define SEQ  2048
#define HID  128
#define NB   32
#define TILE 58            // owned output rows per block
#define GX   36            // ceil(2048/58)
#define MSTR 67            // hT row stride: hT[k][m], k=0..127, m=0..63 (+pad)

typedef float f2    __attribute__((ext_vector_type(2)));
typedef float f32x4 __attribute__((ext_vector_type(4)));
typedef short bf16x8 __attribute__((ext_vector_type(8)));

// split v into bf16 hi + bf16 lo (RNE both); v ~= hi + lo to ~16 mantissa bits
__device__ __forceinline__ void split_bf16(float v, short& h, short& l) {
  unsigned u = __float_as_uint(v);
  unsigned r = (u + 0x7fffu + ((u >> 16) & 1u)) >> 16;
  h = (short)r;
  const float hf = __uint_as_float(r << 16);
  const float lo = v - hf;
  unsigned u2 = __float_as_uint(lo);
  unsigned r2 = (u2 + 0x7fffu + ((u2 >> 16) & 1u)) >> 16;
  l = (short)r2;
}

// ---------------------------------------------------------------------------
// prep_kernel (merged prep_fold + prep_shuffle + zero-init):
//  blocks 0..31  (L=0): compute W' = enc_w2 @ gc1_w tile (32k x 16n) from
//                       LDS-staged operands, split bf16 hi/lo, write frags.
//  blocks 32..95 (L=1,2): split gc2_w / gc3_w directly into frags.
//  block 96: b' = enc_b2 @ gc1_w + gc1_b; zero acc + per-batch counters.
// Frag order (16x16x32 B-frag): dest = bx*512 + l*8 + j  where
//   k = (bx>>3)*32 + (l>>4)*8 + j,  n = (bx&7)*16 + (l&15).
// ---------------------------------------------------------------------------
__global__ __launch_bounds__(256) void prep_kernel(
    const float* __restrict__ enc_w2, const float* __restrict__ enc_b2,
    const float* __restrict__ gc1_w, const float* __restrict__ gc1_b,
    const float* __restrict__ gc2_w, const float* __restrict__ gc3_w,
    short* __restrict__ Wf, float* __restrict__ bp,
    float* __restrict__ acc, unsigned* __restrict__ cnt)
{
  const int tid = threadIdx.x;
  const int bid = blockIdx.x;

  if (bid == 96) {
    if (tid < 128) {
      float s = gc1_b[tid];
      for (int k = 0; k < 128; ++k) s = fmaf(enc_b2[k], gc1_w[k * 128 + tid], s);
      bp[tid] = s;
    }
    for (int i = tid; i < NB * HID; i += 256) acc[i] = 0.f;
    if (tid < NB) cnt[tid] = 0u;
    return;
  }

  const int L = bid >> 5, bx = bid & 31;
  short* hi = Wf + L * 32768;
  short* lo = hi + 16384;

  if (L == 0) {
    // fold on the fly: this block needs enc_w2 rows [k0,k0+32) and
    // gc1_w cols [n0,n0+16); stage both in LDS, then 512 dots of length 128.
    __shared__ float As[32 * 128];   // As[kk][t] = enc_w2[k0+kk][t]
    __shared__ float Bs[128 * 16];   // Bs[t][nn] = gc1_w[t][n0+nn]
    const int k0 = (bx >> 3) * 32, n0 = (bx & 7) * 16;
    for (int i = tid; i < 1024; i += 256)
      ((f32x4*)As)[i] = ((const f32x4*)(enc_w2 + k0 * 128))[i];
    for (int i = tid; i < 512; i += 256) {
      const int t = i >> 2, q = i & 3;
      ((f32x4*)Bs)[i] = *(const f32x4*)(gc1_w + t * 128 + n0 + q * 4);
    }
    __syncthreads();
    #pragma unroll
    for (int e = 0; e < 2; ++e) {
      const int f = tid + e * 256;
      const int l = f >> 3, j = f & 7;
      const float* ar = As + ((l >> 4) * 8 + j) * 128;
      const int nn = l & 15;
      float s0 = 0.f, s1 = 0.f, s2 = 0.f, s3 = 0.f;
      for (int t = 0; t < 128; t += 4) {
        s0 = fmaf(ar[t + 0], Bs[(t + 0) * 16 + nn], s0);
        s1 = fmaf(ar[t + 1], Bs[(t + 1) * 16 + nn], s1);
        s2 = fmaf(ar[t + 2], Bs[(t + 2) * 16 + nn], s2);
        s3 = fmaf(ar[t + 3], Bs[(t + 3) * 16 + nn], s3);
      }
      short h, lw;
      split_bf16((s0 + s1) + (s2 + s3), h, lw);
      hi[bx * 512 + f] = h; lo[bx * 512 + f] = lw;
    }
  } else {
    const float* __restrict__ SW = (L == 1) ? gc2_w : gc3_w;
    const int ks = bx >> 3, nt = bx & 7;
    for (int f = tid; f < 512; f += 256) {
      const int l = f >> 3, j = f & 7;
      const int k = ks * 32 + (l >> 4) * 8 + j;
      const int n = nt * 16 + (l & 15);
      short h, lw;
      split_bf16(SW[k * 128 + n], h, lw);
      hi[bx * 512 + f] = h; lo[bx * 512 + f] = lw;
    }
  }
}

// ---------------------------------------------------------------------------
// Fused enc1 -> [enc2*gc1 folded] -> gc2 -> gc3 -> pool -> (last block per
// batch) classifier.  MFMA bf16x3.  Block = (58-row seq tile, batch),
// 256 thr = 4 waves; wave w owns rows m = w*16 .. w*16+15 of the 64 staged
// rows (s = s0-3+m).  Activations in transposed LDS hT[k][m].
// Pool partials accumulated via device-scope atomicAdd into acc[b][c]; the
// last-arriving block of each batch (per-batch counter) runs the classifier.
// Validity telescoping: t1 ok m in [0,63]&inseq -> h1 [1,62] -> h2 [2,61]
// -> t3 ok [2,61] -> pooled rows m in [3,60] need t3[m-1..m+1] in [2,61]. OK.
// ---------------------------------------------------------------------------
__global__ __launch_bounds__(256) void fused_kernel(
    const float* __restrict__ x,
    const float* __restrict__ enc_w1, const float* __restrict__ enc_b1,
    const short* __restrict__ Wf, const float* __restrict__ bp,
    const float* __restrict__ gc2_b, const float* __restrict__ gc3_b,
    float* __restrict__ acc, unsigned* __restrict__ cnt,
    const float* __restrict__ cls_w1, const float* __restrict__ cls_b1,
    const float* __restrict__ cls_w2, const float* __restrict__ cls_b2,
    float* __restrict__ out)
{
  __shared__ float hT[HID * MSTR];      // 34304 B, [k][m]
  __shared__ float wsmall[7 * HID];     // enc_w1 (6x128) + enc_b1
  __shared__ float psum[256];
  __shared__ int lastf;

  const int tid  = threadIdx.x;
  const int lane = tid & 63;
  const int w    = tid >> 6;            // wave id 0..3
  const int gxb  = blockIdx.x, b = blockIdx.y;
  const int s0   = gxb * TILE;

  // ---------------- enc1 (fp32 VALU): lane = row m, wave = 32-col group ----
  for (int f = tid; f < 7 * HID; f += 256)
    wsmall[f] = (f < 6 * HID) ? enc_w1[f] : enc_b1[f - 6 * HID];

  const int sm = s0 - 3 + lane;
  float xv[6];
  if (sm >= 0 && sm < SEQ) {
    const f2* xp = (const f2*)(x + ((long long)b * SEQ + sm) * 6);
    const f2 a0 = xp[0], a1 = xp[1], a2 = xp[2];
    xv[0] = a0.x; xv[1] = a0.y; xv[2] = a1.x;
    xv[3] = a1.y; xv[4] = a2.x; xv[5] = a2.y;
  } else {
    #pragma unroll
    for (int k = 0; k < 6; ++k) xv[k] = 0.f;
  }
  __syncthreads();
  {
    const int c0 = w * 32;
    float4 a4[8];
    #pragma unroll
    for (int q = 0; q < 8; ++q) a4[q] = make_float4(0.f, 0.f, 0.f, 0.f);
    #pragma unroll
    for (int k = 0; k < 6; ++k) {
      #pragma unroll
      for (int q = 0; q < 8; ++q) {
        const float4 wv = *(const float4*)&wsmall[k * HID + c0 + q * 4];
        a4[q].x = fmaf(xv[k], wv.x, a4[q].x);
        a4[q].y = fmaf(xv[k], wv.y, a4[q].y);
        a4[q].z = fmaf(xv[k], wv.z, a4[q].z);
        a4[q].w = fmaf(xv[k], wv.w, a4[q].w);
      }
    }
    #pragma unroll
    for (int q = 0; q < 8; ++q) {
      const float4 bb = *(const float4*)&wsmall[6 * HID + c0 + q * 4];
      const int c = c0 + q * 4;
      hT[(c + 0) * MSTR + lane] = fmaxf(a4[q].x + bb.x, 0.f);
      hT[(c + 1) * MSTR + lane] = fmaxf(a4[q].y + bb.y, 0.f);
      hT[(c + 2) * MSTR + lane] = fmaxf(a4[q].z + bb.z, 0.f);
      hT[(c + 3) * MSTR + lane] = fmaxf(a4[q].w + bb.w, 0.f);
    }
  }
  __syncthreads();

  // ---------------- 3 MFMA layers ----------------
  const int mt   = w * 16 + (lane & 15);       // A-frag target row
  const int koct = (lane >> 4) * 8;            // A-frag k-octet base
  const int stt  = s0 - 3 + mt;
  const float invdA = (stt == 0 || stt == SEQ - 1) ? (1.0f / (2.0f + 1e-8f))
                                                   : (1.0f / (3.0f + 1e-8f));
  const int mm = (mt == 0) ? 0 : mt - 1;
  const int mp = (mt == 63) ? 63 : mt + 1;

  #pragma unroll 1
  for (int L = 0; L < 3; ++L) {
    const short* WfL = Wf + L * 32768;
    const bf16x8* Bhi = (const bf16x8*)WfL;
    const bf16x8* Blo = (const bf16x8*)(WfL + 16384);
    const float* bias = (L == 0) ? bp : (L == 1) ? gc2_b : gc3_b;

    f32x4 acc_[8];
    #pragma unroll
    for (int nt = 0; nt < 8; ++nt) acc_[nt] = (f32x4){0.f, 0.f, 0.f, 0.f};

    #pragma unroll 1
    for (int ks = 0; ks < 4; ++ks) {
      // B-frags first (VMEM latency hides behind A assembly)
      const int fb = ks * 512 + lane;
      bf16x8 bh[8], bl[8];
      #pragma unroll
      for (int nt = 0; nt < 8; ++nt) {
        bh[nt] = Bhi[fb + nt * 64];
        bl[nt] = Blo[fb + nt * 64];
      }
      // A-frag: read hT (agg+relu for L>0), split hi/lo
      bf16x8 ah, al;
      const float* pa = &hT[(ks * 32 + koct) * MSTR];
      #pragma unroll
      for (int j = 0; j < 8; ++j) {
        float v;
        if (L == 0) {
          v = pa[j * MSTR + mt];
        } else {
          v = (pa[j * MSTR + mm] + pa[j * MSTR + mt] + pa[j * MSTR + mp]) * invdA;
          v = fmaxf(v, 0.f);
        }
        short h, lo;
        split_bf16(v, h, lo);
        ah[j] = h; al[j] = lo;
      }
      #pragma unroll
      for (int nt = 0; nt < 8; ++nt) {
        acc_[nt] = __builtin_amdgcn_mfma_f32_16x16x32_bf16(ah, bh[nt], acc_[nt], 0, 0, 0);
        acc_[nt] = __builtin_amdgcn_mfma_f32_16x16x32_bf16(ah, bl[nt], acc_[nt], 0, 0, 0);
        acc_[nt] = __builtin_amdgcn_mfma_f32_16x16x32_bf16(al, bh[nt], acc_[nt], 0, 0, 0);
      }
    }
    __syncthreads();   // all hT reads of this layer done

    // epilogue: t = inseq ? acc + bias : 0 -> hT[n][m]  (C/D layout scatter)
    {
      const int n0 = lane & 15;
      const int mrow0 = w * 16 + (lane >> 4) * 4;
      #pragma unroll
      for (int nt = 0; nt < 8; ++nt) {
        const float bn = bias[nt * 16 + n0];
        float* pw = &hT[(nt * 16 + n0) * MSTR];
        #pragma unroll
        for (int r = 0; r < 4; ++r) {
          const int m = mrow0 + r;
          const int s = s0 - 3 + m;
          const bool vld = (s >= 0 && s < SEQ);
          pw[m] = vld ? (acc_[nt][r] + bn) : 0.f;
        }
      }
    }
    __syncthreads();   // publish t for next layer / pool
  }

  // ---------------- pool: h3 = relu(agg(t3)); sum owned rows ----------------
  {
    const int c = tid & 127, half = tid >> 7;
    float ps = 0.f;
    const float* pc = &hT[c * MSTR];
    #pragma unroll 1
    for (int r = 0; r < 29; ++r) {
      const int m = 3 + half * 29 + r;
      const int s = s0 + half * 29 + r;
      if (s < SEQ) {
        const float invd = (s == 0 || s == SEQ - 1) ? (1.0f / (2.0f + 1e-8f))
                                                    : (1.0f / (3.0f + 1e-8f));
        ps += fmaxf((pc[m - 1] + pc[m] + pc[m + 1]) * invd, 0.f);
      }
    }
    psum[tid] = ps;
  }
  __syncthreads();

  // ---------------- accumulate pooled partials (device-scope atomics) ------
  if (tid < 128)
    atomicAdd(&acc[(long long)b * HID + tid], psum[tid] + psum[tid + 128]);
  __syncthreads();          // vmcnt drained -> our adds complete at L2-coherent point
  if (tid == 0) {
    __threadfence();
    unsigned old = atomicAdd(&cnt[b], 1u);
    lastf = (old == GX - 1) ? 1 : 0;
  }
  __syncthreads();
  if (!lastf) return;

  // ---------------- classifier (last block of batch b only) ----------------
  if (tid < 128) {
    const float v = __hip_atomic_load(&acc[(long long)b * HID + tid],
                                      __ATOMIC_RELAXED, __HIP_MEMORY_SCOPE_AGENT);
    psum[tid] = v * (1.0f / 2048.0f);
  }
  __syncthreads();
  if (tid < 64) {
    float h = cls_b1[tid];
    for (int k = 0; k < 128; ++k) h = fmaf(psum[k], cls_w1[k * 64 + tid], h);
    psum[128 + tid] = fmaxf(h, 0.f);
  }
  __syncthreads();
  if (tid < 3) {
    float o = cls_b2[tid];
    for (int k = 0; k < 64; ++k) o = fmaf(psum[128 + k], cls_w2[k * 3 + tid], o);
    out[b * 3 + tid] = o;
  }
}

extern "C" void kernel_launch(void* const* d_in, const int* in_sizes, int n_in,
                              void* d_out, int out_size, void* d_ws, size_t ws_size,
                              hipStream_t stream) {
  (void)in_sizes; (void)n_in; (void)out_size; (void)ws_size;
  const float* x      = (const float*)d_in[0];
  const float* enc_w1 = (const float*)d_in[1];
  const float* enc_b1 = (const float*)d_in[2];
  const float* enc_w2 = (const float*)d_in[3];
  const float* enc_b2 = (const float*)d_in[4];
  const float* gc1_w  = (const float*)d_in[5];
  const float* gc1_b  = (const float*)d_in[6];
  const float* gc2_w  = (const float*)d_in[7];
  const float* gc2_b  = (const float*)d_in[8];
  const float* gc3_w  = (const float*)d_in[9];
  const float* gc3_b  = (const float*)d_in[10];
  const float* cls_w1 = (const float*)d_in[11];
  const float* cls_b1 = (const float*)d_in[12];
  const float* cls_w2 = (const float*)d_in[13];
  const float* cls_b2 = (const float*)d_in[14];

  // workspace layout (rewritten fully every launch — ws is re-poisoned)
  float* bpv     = (float*)d_ws;                     // 128 f32
  short* Wfrag   = (short*)(bpv + 128);              // 3 * 2 * 16384 bf16
  float* accb    = (float*)(Wfrag + 3 * 2 * 16384);  // NB*HID f32 (zeroed by prep)
  unsigned* cntb = (unsigned*)(accb + NB * HID);     // NB u32   (zeroed by prep)

  prep_kernel<<<dim3(97), 256, 0, stream>>>(enc_w2, enc_b2, gc1_w, gc1_b,
                                            gc2_w, gc3_w, Wfrag, bpv, accb, cntb);
  fused_kernel<<<dim3(GX, NB), 256, 0, stream>>>(
      x, enc_w1, enc_b1, Wfrag, bpv, gc2_b, gc3_b, accb, cntb,
      cls_w1, cls_b1, cls_w2, cls_b2, (float*)d_out);
}

// Round 2
// 145.169 us; speedup vs baseline: 1.0156x; 1.0156x over previous
//
#include <hip/hip_runtime.h>

#define SEQ  2048
#define HID  128
#define NB   32
#define TILE 58            // owned output rows per block
#define GX   36            // ceil(2048/58)
#define MSTR 67            // hT row stride: hT[k][m], k=0..127, m=0..63 (+pad)

typedef float f2    __attribute__((ext_vector_type(2)));
typedef float f32x4 __attribute__((ext_vector_type(4)));
typedef short bf16x8 __attribute__((ext_vector_type(8)));

// split v into bf16 hi + bf16 lo (RNE both); v ~= hi + lo to ~16 mantissa bits
__device__ __forceinline__ void split_bf16(float v, short& h, short& l) {
  unsigned u = __float_as_uint(v);
  unsigned r = (u + 0x7fffu + ((u >> 16) & 1u)) >> 16;
  h = (short)r;
  const float hf = __uint_as_float(r << 16);
  const float lo = v - hf;
  unsigned u2 = __float_as_uint(lo);
  unsigned r2 = (u2 + 0x7fffu + ((u2 >> 16) & 1u)) >> 16;
  l = (short)r2;
}

// ---------------------------------------------------------------------------
// prep_kernel (merged fold + shuffle + counter init):
//  blocks 0..31  (L=0): W' = enc_w2 @ gc1_w tile (32k x 16n) from LDS-staged
//                       operands, split bf16 hi/lo, write frags.
//  blocks 32..95 (L=1,2): split gc2_w / gc3_w directly into frags.
//  block 96: b' = enc_b2 @ gc1_w + gc1_b; zero per-batch arrival counters.
// Frag order (16x16x32 B-frag): dest = bx*512 + l*8 + j  where
//   k = (bx>>3)*32 + (l>>4)*8 + j,  n = (bx&7)*16 + (l&15).
// ---------------------------------------------------------------------------
__global__ __launch_bounds__(256) void prep_kernel(
    const float* __restrict__ enc_w2, const float* __restrict__ enc_b2,
    const float* __restrict__ gc1_w, const float* __restrict__ gc1_b,
    const float* __restrict__ gc2_w, const float* __restrict__ gc3_w,
    short* __restrict__ Wf, float* __restrict__ bp, unsigned* __restrict__ cnt)
{
  const int tid = threadIdx.x;
  const int bid = blockIdx.x;

  if (bid == 96) {
    if (tid < 128) {
      float s = gc1_b[tid];
      for (int k = 0; k < 128; ++k) s = fmaf(enc_b2[k], gc1_w[k * 128 + tid], s);
      bp[tid] = s;
    }
    if (tid < NB) cnt[tid] = 0u;
    return;
  }

  const int L = bid >> 5, bx = bid & 31;
  short* hi = Wf + L * 32768;
  short* lo = hi + 16384;

  if (L == 0) {
    // fold on the fly: this block needs enc_w2 rows [k0,k0+32) and
    // gc1_w cols [n0,n0+16); stage both in LDS, then 512 dots of length 128.
    __shared__ float As[32 * 128];   // As[kk][t] = enc_w2[k0+kk][t]
    __shared__ float Bs[128 * 16];   // Bs[t][nn] = gc1_w[t][n0+nn]
    const int k0 = (bx >> 3) * 32, n0 = (bx & 7) * 16;
    for (int i = tid; i < 1024; i += 256)
      ((f32x4*)As)[i] = ((const f32x4*)(enc_w2 + k0 * 128))[i];
    for (int i = tid; i < 512; i += 256) {
      const int t = i >> 2, q = i & 3;
      ((f32x4*)Bs)[i] = *(const f32x4*)(gc1_w + t * 128 + n0 + q * 4);
    }
    __syncthreads();
    #pragma unroll
    for (int e = 0; e < 2; ++e) {
      const int f = tid + e * 256;
      const int l = f >> 3, j = f & 7;
      const float* ar = As + ((l >> 4) * 8 + j) * 128;
      const int nn = l & 15;
      float s0 = 0.f, s1 = 0.f, s2 = 0.f, s3 = 0.f;
      for (int t = 0; t < 128; t += 4) {
        s0 = fmaf(ar[t + 0], Bs[(t + 0) * 16 + nn], s0);
        s1 = fmaf(ar[t + 1], Bs[(t + 1) * 16 + nn], s1);
        s2 = fmaf(ar[t + 2], Bs[(t + 2) * 16 + nn], s2);
        s3 = fmaf(ar[t + 3], Bs[(t + 3) * 16 + nn], s3);
      }
      short h, lw;
      split_bf16((s0 + s1) + (s2 + s3), h, lw);
      hi[bx * 512 + f] = h; lo[bx * 512 + f] = lw;
    }
  } else {
    const float* __restrict__ SW = (L == 1) ? gc2_w : gc3_w;
    const int ks = bx >> 3, nt = bx & 7;
    for (int f = tid; f < 512; f += 256) {
      const int l = f >> 3, j = f & 7;
      const int k = ks * 32 + (l >> 4) * 8 + j;
      const int n = nt * 16 + (l & 15);
      short h, lw;
      split_bf16(SW[k * 128 + n], h, lw);
      hi[bx * 512 + f] = h; lo[bx * 512 + f] = lw;
    }
  }
}

// ---------------------------------------------------------------------------
// Fused enc1 -> [enc2*gc1 folded] -> gc2 -> gc3 -> pool -> (last block per
// batch) classifier.  MFMA bf16x3.  Block = (58-row seq tile, batch),
// 256 thr = 4 waves; wave w owns rows m = w*16 .. w*16+15 of the 64 staged
// rows (s = s0-3+m).  Activations in transposed LDS hT[k][m].
// Handoff: per-block pool partials stored with agent-scope (sc1) plain
// stores (no contention), per-thread vmcnt drain, ONE acq_rel counter RMW
// per block; last-arriving block per batch reads the 36 partials (agent
// scope, bypasses stale XCD L2) and runs the classifier inline.
// Validity telescoping: t1 ok m in [0,63]&inseq -> h1 [1,62] -> h2 [2,61]
// -> t3 ok [2,61] -> pooled rows m in [3,60] need t3[m-1..m+1] in [2,61]. OK.
// ---------------------------------------------------------------------------
__global__ __launch_bounds__(256) void fused_kernel(
    const float* __restrict__ x,
    const float* __restrict__ enc_w1, const float* __restrict__ enc_b1,
    const short* __restrict__ Wf, const float* __restrict__ bp,
    const float* __restrict__ gc2_b, const float* __restrict__ gc3_b,
    float* __restrict__ partial, unsigned* __restrict__ cnt,
    const float* __restrict__ cls_w1, const float* __restrict__ cls_b1,
    const float* __restrict__ cls_w2, const float* __restrict__ cls_b2,
    float* __restrict__ out)
{
  __shared__ float hT[HID * MSTR];      // 34304 B, [k][m]
  __shared__ float wsmall[7 * HID];     // enc_w1 (6x128) + enc_b1
  __shared__ float psum[256];
  __shared__ int lastf;

  const int tid  = threadIdx.x;
  const int lane = tid & 63;
  const int w    = tid >> 6;            // wave id 0..3
  const int gxb  = blockIdx.x, b = blockIdx.y;
  const int s0   = gxb * TILE;

  // ---------------- enc1 (fp32 VALU): lane = row m, wave = 32-col group ----
  for (int f = tid; f < 7 * HID; f += 256)
    wsmall[f] = (f < 6 * HID) ? enc_w1[f] : enc_b1[f - 6 * HID];

  const int sm = s0 - 3 + lane;
  float xv[6];
  if (sm >= 0 && sm < SEQ) {
    const f2* xp = (const f2*)(x + ((long long)b * SEQ + sm) * 6);
    const f2 a0 = xp[0], a1 = xp[1], a2 = xp[2];
    xv[0] = a0.x; xv[1] = a0.y; xv[2] = a1.x;
    xv[3] = a1.y; xv[4] = a2.x; xv[5] = a2.y;
  } else {
    #pragma unroll
    for (int k = 0; k < 6; ++k) xv[k] = 0.f;
  }
  __syncthreads();
  {
    const int c0 = w * 32;
    float4 a4[8];
    #pragma unroll
    for (int q = 0; q < 8; ++q) a4[q] = make_float4(0.f, 0.f, 0.f, 0.f);
    #pragma unroll
    for (int k = 0; k < 6; ++k) {
      #pragma unroll
      for (int q = 0; q < 8; ++q) {
        const float4 wv = *(const float4*)&wsmall[k * HID + c0 + q * 4];
        a4[q].x = fmaf(xv[k], wv.x, a4[q].x);
        a4[q].y = fmaf(xv[k], wv.y, a4[q].y);
        a4[q].z = fmaf(xv[k], wv.z, a4[q].z);
        a4[q].w = fmaf(xv[k], wv.w, a4[q].w);
      }
    }
    #pragma unroll
    for (int q = 0; q < 8; ++q) {
      const float4 bb = *(const float4*)&wsmall[6 * HID + c0 + q * 4];
      const int c = c0 + q * 4;
      hT[(c + 0) * MSTR + lane] = fmaxf(a4[q].x + bb.x, 0.f);
      hT[(c + 1) * MSTR + lane] = fmaxf(a4[q].y + bb.y, 0.f);
      hT[(c + 2) * MSTR + lane] = fmaxf(a4[q].z + bb.z, 0.f);
      hT[(c + 3) * MSTR + lane] = fmaxf(a4[q].w + bb.w, 0.f);
    }
  }
  __syncthreads();

  // ---------------- 3 MFMA layers ----------------
  const int mt   = w * 16 + (lane & 15);       // A-frag target row
  const int koct = (lane >> 4) * 8;            // A-frag k-octet base
  const int stt  = s0 - 3 + mt;
  const float invdA = (stt == 0 || stt == SEQ - 1) ? (1.0f / (2.0f + 1e-8f))
                                                   : (1.0f / (3.0f + 1e-8f));
  const int mm = (mt == 0) ? 0 : mt - 1;
  const int mp = (mt == 63) ? 63 : mt + 1;

  #pragma unroll 1
  for (int L = 0; L < 3; ++L) {
    const short* WfL = Wf + L * 32768;
    const bf16x8* Bhi = (const bf16x8*)WfL;
    const bf16x8* Blo = (const bf16x8*)(WfL + 16384);
    const float* bias = (L == 0) ? bp : (L == 1) ? gc2_b : gc3_b;

    f32x4 acc_[8];
    #pragma unroll
    for (int nt = 0; nt < 8; ++nt) acc_[nt] = (f32x4){0.f, 0.f, 0.f, 0.f};

    #pragma unroll 1
    for (int ks = 0; ks < 4; ++ks) {
      // B-frags first (VMEM latency hides behind A assembly)
      const int fb = ks * 512 + lane;
      bf16x8 bh[8], bl[8];
      #pragma unroll
      for (int nt = 0; nt < 8; ++nt) {
        bh[nt] = Bhi[fb + nt * 64];
        bl[nt] = Blo[fb + nt * 64];
      }
      // A-frag: read hT (agg+relu for L>0), split hi/lo
      bf16x8 ah, al;
      const float* pa = &hT[(ks * 32 + koct) * MSTR];
      #pragma unroll
      for (int j = 0; j < 8; ++j) {
        float v;
        if (L == 0) {
          v = pa[j * MSTR + mt];
        } else {
          v = (pa[j * MSTR + mm] + pa[j * MSTR + mt] + pa[j * MSTR + mp]) * invdA;
          v = fmaxf(v, 0.f);
        }
        short h, lo;
        split_bf16(v, h, lo);
        ah[j] = h; al[j] = lo;
      }
      #pragma unroll
      for (int nt = 0; nt < 8; ++nt) {
        acc_[nt] = __builtin_amdgcn_mfma_f32_16x16x32_bf16(ah, bh[nt], acc_[nt], 0, 0, 0);
        acc_[nt] = __builtin_amdgcn_mfma_f32_16x16x32_bf16(ah, bl[nt], acc_[nt], 0, 0, 0);
        acc_[nt] = __builtin_amdgcn_mfma_f32_16x16x32_bf16(al, bh[nt], acc_[nt], 0, 0, 0);
      }
    }
    __syncthreads();   // all hT reads of this layer done

    // epilogue: t = inseq ? acc + bias : 0 -> hT[n][m]  (C/D layout scatter)
    {
      const int n0 = lane & 15;
      const int mrow0 = w * 16 + (lane >> 4) * 4;
      #pragma unroll
      for (int nt = 0; nt < 8; ++nt) {
        const float bn = bias[nt * 16 + n0];
        float* pw = &hT[(nt * 16 + n0) * MSTR];
        #pragma unroll
        for (int r = 0; r < 4; ++r) {
          const int m = mrow0 + r;
          const int s = s0 - 3 + m;
          const bool vld = (s >= 0 && s < SEQ);
          pw[m] = vld ? (acc_[nt][r] + bn) : 0.f;
        }
      }
    }
    __syncthreads();   // publish t for next layer / pool
  }

  // ---------------- pool: h3 = relu(agg(t3)); sum owned rows ----------------
  {
    const int c = tid & 127, half = tid >> 7;
    float ps = 0.f;
    const float* pc = &hT[c * MSTR];
    #pragma unroll 1
    for (int r = 0; r < 29; ++r) {
      const int m = 3 + half * 29 + r;
      const int s = s0 + half * 29 + r;
      if (s < SEQ) {
        const float invd = (s == 0 || s == SEQ - 1) ? (1.0f / (2.0f + 1e-8f))
                                                    : (1.0f / (3.0f + 1e-8f));
        ps += fmaxf((pc[m - 1] + pc[m] + pc[m + 1]) * invd, 0.f);
      }
    }
    psum[tid] = ps;
  }
  __syncthreads();

  // ---------------- publish partial (agent-scope stores, no contention) ----
  if (tid < 128) {
    __hip_atomic_store(&partial[((long long)b * GX + gxb) * HID + tid],
                       psum[tid] + psum[tid + 128],
                       __ATOMIC_RELAXED, __HIP_MEMORY_SCOPE_AGENT);
  }
  // each thread drains its own store acks (coherent point) before barrier
  asm volatile("s_waitcnt vmcnt(0)" ::: "memory");
  __syncthreads();
  if (tid == 0) {
    const unsigned old = __hip_atomic_fetch_add(&cnt[b], 1u, __ATOMIC_ACQ_REL,
                                                __HIP_MEMORY_SCOPE_AGENT);
    lastf = (old == GX - 1) ? 1 : 0;
  }
  __syncthreads();
  if (!lastf) return;

  // ---------------- classifier (last block of batch b only) ----------------
  if (tid < 128) {
    float a = 0.f;
    #pragma unroll
    for (int g = 0; g < GX; ++g)
      a += __hip_atomic_load(&partial[((long long)b * GX + g) * HID + tid],
                             __ATOMIC_RELAXED, __HIP_MEMORY_SCOPE_AGENT);
    psum[tid] = a * (1.0f / 2048.0f);
  }
  __syncthreads();
  if (tid < 64) {
    float h = cls_b1[tid];
    for (int k = 0; k < 128; ++k) h = fmaf(psum[k], cls_w1[k * 64 + tid], h);
    psum[128 + tid] = fmaxf(h, 0.f);
  }
  __syncthreads();
  if (tid < 3) {
    float o = cls_b2[tid];
    for (int k = 0; k < 64; ++k) o = fmaf(psum[128 + k], cls_w2[k * 3 + tid], o);
    out[b * 3 + tid] = o;
  }
}

extern "C" void kernel_launch(void* const* d_in, const int* in_sizes, int n_in,
                              void* d_out, int out_size, void* d_ws, size_t ws_size,
                              hipStream_t stream) {
  (void)in_sizes; (void)n_in; (void)out_size; (void)ws_size;
  const float* x      = (const float*)d_in[0];
  const float* enc_w1 = (const float*)d_in[1];
  const float* enc_b1 = (const float*)d_in[2];
  const float* enc_w2 = (const float*)d_in[3];
  const float* enc_b2 = (const float*)d_in[4];
  const float* gc1_w  = (const float*)d_in[5];
  const float* gc1_b  = (const float*)d_in[6];
  const float* gc2_w  = (const float*)d_in[7];
  const float* gc2_b  = (const float*)d_in[8];
  const float* gc3_w  = (const float*)d_in[9];
  const float* gc3_b  = (const float*)d_in[10];
  const float* cls_w1 = (const float*)d_in[11];
  const float* cls_b1 = (const float*)d_in[12];
  const float* cls_w2 = (const float*)d_in[13];
  const float* cls_b2 = (const float*)d_in[14];

  // workspace layout (rewritten fully every launch — ws is re-poisoned)
  float* bpv     = (float*)d_ws;                     // 128 f32
  short* Wfrag   = (short*)(bpv + 128);              // 3 * 2 * 16384 bf16
  float* partial = (float*)(Wfrag + 3 * 2 * 16384);  // NB*GX*HID f32 (all slots rewritten)
  unsigned* cntb = (unsigned*)(partial + (long long)NB * GX * HID);  // NB u32 (zeroed by prep)

  prep_kernel<<<dim3(97), 256, 0, stream>>>(enc_w2, enc_b2, gc1_w, gc1_b,
                                            gc2_w, gc3_w, Wfrag, bpv, cntb);
  fused_kernel<<<dim3(GX, NB), 256, 0, stream>>>(
      x, enc_w1, enc_b1, Wfrag, bpv, gc2_b, gc3_b, partial, cntb,
      cls_w1, cls_b1, cls_w2, cls_b2, (float*)d_out);
}

// Round 3
// 137.138 us; speedup vs baseline: 1.0751x; 1.0586x over previous
//
#include <hip/hip_runtime.h>

#define SEQ  2048
#define HID  128
#define NB   32
#define TILE 58            // owned output rows per block
#define GX   36            // ceil(2048/58)
#define MSTR 67            // hT row stride: hT[k][m], k=0..127, m=0..63 (+pad)

typedef float f2    __attribute__((ext_vector_type(2)));
typedef float f32x4 __attribute__((ext_vector_type(4)));
typedef short bf16x8 __attribute__((ext_vector_type(8)));
typedef unsigned u32x4 __attribute__((ext_vector_type(4)));

// split v into bf16 hi + bf16 lo (RNE both); v ~= hi + lo to ~16 mantissa bits
__device__ __forceinline__ void split_bf16(float v, short& h, short& l) {
  unsigned u = __float_as_uint(v);
  unsigned r = (u + 0x7fffu + ((u >> 16) & 1u)) >> 16;
  h = (short)r;
  const float hf = __uint_as_float(r << 16);
  const float lo = v - hf;
  unsigned u2 = __float_as_uint(lo);
  unsigned r2 = (u2 + 0x7fffu + ((u2 >> 16) & 1u)) >> 16;
  l = (short)r2;
}

// packed RNE bf16 conversion of a float pair: lo16 = bf16(a), hi16 = bf16(b).
// Same rounding as split_bf16's manual RNE -> bitwise-identical results.
__device__ __forceinline__ unsigned cvt_pk_bf16(float a, float b) {
  unsigned r;
  asm("v_cvt_pk_bf16_f32 %0, %1, %2" : "=v"(r) : "v"(a), "v"(b));
  return r;
}

// ---------------------------------------------------------------------------
// prep_kernel (merged fold + shuffle + counter init):
//  blocks 0..31  (L=0): W' = enc_w2 @ gc1_w tile (32k x 16n) from LDS-staged
//                       operands, split bf16 hi/lo, write frags.
//  blocks 32..95 (L=1,2): split gc2_w / gc3_w directly into frags.
//  block 96: b' = enc_b2 @ gc1_w + gc1_b; zero per-batch arrival counters.
// Frag order (16x16x32 B-frag): dest = bx*512 + l*8 + j  where
//   k = (bx>>3)*32 + (l>>4)*8 + j,  n = (bx&7)*16 + (l&15).
// ---------------------------------------------------------------------------
__global__ __launch_bounds__(256) void prep_kernel(
    const float* __restrict__ enc_w2, const float* __restrict__ enc_b2,
    const float* __restrict__ gc1_w, const float* __restrict__ gc1_b,
    const float* __restrict__ gc2_w, const float* __restrict__ gc3_w,
    short* __restrict__ Wf, float* __restrict__ bp, unsigned* __restrict__ cnt)
{
  const int tid = threadIdx.x;
  const int bid = blockIdx.x;

  if (bid == 96) {
    if (tid < 128) {
      float s = gc1_b[tid];
      for (int k = 0; k < 128; ++k) s = fmaf(enc_b2[k], gc1_w[k * 128 + tid], s);
      bp[tid] = s;
    }
    if (tid < NB) cnt[tid] = 0u;
    return;
  }

  const int L = bid >> 5, bx = bid & 31;
  short* hi = Wf + L * 32768;
  short* lo = hi + 16384;

  if (L == 0) {
    // fold on the fly: this block needs enc_w2 rows [k0,k0+32) and
    // gc1_w cols [n0,n0+16); stage both in LDS, then 512 dots of length 128.
    __shared__ float As[32 * 128];   // As[kk][t] = enc_w2[k0+kk][t]
    __shared__ float Bs[128 * 16];   // Bs[t][nn] = gc1_w[t][n0+nn]
    const int k0 = (bx >> 3) * 32, n0 = (bx & 7) * 16;
    for (int i = tid; i < 1024; i += 256)
      ((f32x4*)As)[i] = ((const f32x4*)(enc_w2 + k0 * 128))[i];
    for (int i = tid; i < 512; i += 256) {
      const int t = i >> 2, q = i & 3;
      ((f32x4*)Bs)[i] = *(const f32x4*)(gc1_w + t * 128 + n0 + q * 4);
    }
    __syncthreads();
    #pragma unroll
    for (int e = 0; e < 2; ++e) {
      const int f = tid + e * 256;
      const int l = f >> 3, j = f & 7;
      const float* ar = As + ((l >> 4) * 8 + j) * 128;
      const int nn = l & 15;
      float s0 = 0.f, s1 = 0.f, s2 = 0.f, s3 = 0.f;
      for (int t = 0; t < 128; t += 4) {
        s0 = fmaf(ar[t + 0], Bs[(t + 0) * 16 + nn], s0);
        s1 = fmaf(ar[t + 1], Bs[(t + 1) * 16 + nn], s1);
        s2 = fmaf(ar[t + 2], Bs[(t + 2) * 16 + nn], s2);
        s3 = fmaf(ar[t + 3], Bs[(t + 3) * 16 + nn], s3);
      }
      short h, lw;
      split_bf16((s0 + s1) + (s2 + s3), h, lw);
      hi[bx * 512 + f] = h; lo[bx * 512 + f] = lw;
    }
  } else {
    const float* __restrict__ SW = (L == 1) ? gc2_w : gc3_w;
    const int ks = bx >> 3, nt = bx & 7;
    for (int f = tid; f < 512; f += 256) {
      const int l = f >> 3, j = f & 7;
      const int k = ks * 32 + (l >> 4) * 8 + j;
      const int n = nt * 16 + (l & 15);
      short h, lw;
      split_bf16(SW[k * 128 + n], h, lw);
      hi[bx * 512 + f] = h; lo[bx * 512 + f] = lw;
    }
  }
}

// ---------------------------------------------------------------------------
// Fused enc1 -> [enc2*gc1 folded] -> gc2 -> gc3 -> pool -> (last block per
// batch) classifier.  MFMA bf16x3.  Block = (58-row seq tile, batch),
// 256 thr = 4 waves; wave w owns rows m = w*16 .. w*16+15 of the 64 staged
// rows (s = s0-3+m).  Activations in transposed LDS hT[k][m].
// Handoff: per-block pool partials stored with agent-scope plain stores
// (no contention), per-thread vmcnt drain (stores ack from the coherent
// point), then ONE RELAXED counter RMW per block — NO acq_rel: the release
// fence at agent scope compiles to an L2 writeback/invalidate which evicted
// the hot Wfrag L2 working set 1152x (round-2 lesson: +400KB FETCH, +13us).
// Ordering is physically sound: vmcnt(0) drains sc1 stores to the coherent
// point before the RMW issues; counter total-order at the coherent point +
// agent-scope (cache-bypassing) loads in the last block do the rest.
// Validity telescoping: t1 ok m in [0,63]&inseq -> h1 [1,62] -> h2 [2,61]
// -> t3 ok [2,61] -> pooled rows m in [3,60] need t3[m-1..m+1] in [2,61]. OK.
// ---------------------------------------------------------------------------
__global__ __launch_bounds__(256) void fused_kernel(
    const float* __restrict__ x,
    const float* __restrict__ enc_w1, const float* __restrict__ enc_b1,
    const short* __restrict__ Wf, const float* __restrict__ bp,
    const float* __restrict__ gc2_b, const float* __restrict__ gc3_b,
    float* __restrict__ partial, unsigned* __restrict__ cnt,
    const float* __restrict__ cls_w1, const float* __restrict__ cls_b1,
    const float* __restrict__ cls_w2, const float* __restrict__ cls_b2,
    float* __restrict__ out)
{
  __shared__ float hT[HID * MSTR];      // 34304 B, [k][m]
  __shared__ float wsmall[7 * HID];     // enc_w1 (6x128) + enc_b1
  __shared__ float psum[256];
  __shared__ int lastf;

  const int tid  = threadIdx.x;
  const int lane = tid & 63;
  const int w    = tid >> 6;            // wave id 0..3
  const int gxb  = blockIdx.x, b = blockIdx.y;
  const int s0   = gxb * TILE;

  // ---------------- enc1 (fp32 VALU): lane = row m, wave = 32-col group ----
  for (int f = tid; f < 7 * HID; f += 256)
    wsmall[f] = (f < 6 * HID) ? enc_w1[f] : enc_b1[f - 6 * HID];

  const int sm = s0 - 3 + lane;
  float xv[6];
  if (sm >= 0 && sm < SEQ) {
    const f2* xp = (const f2*)(x + ((long long)b * SEQ + sm) * 6);
    const f2 a0 = xp[0], a1 = xp[1], a2 = xp[2];
    xv[0] = a0.x; xv[1] = a0.y; xv[2] = a1.x;
    xv[3] = a1.y; xv[4] = a2.x; xv[5] = a2.y;
  } else {
    #pragma unroll
    for (int k = 0; k < 6; ++k) xv[k] = 0.f;
  }
  __syncthreads();
  {
    const int c0 = w * 32;
    float4 a4[8];
    #pragma unroll
    for (int q = 0; q < 8; ++q) a4[q] = make_float4(0.f, 0.f, 0.f, 0.f);
    #pragma unroll
    for (int k = 0; k < 6; ++k) {
      #pragma unroll
      for (int q = 0; q < 8; ++q) {
        const float4 wv = *(const float4*)&wsmall[k * HID + c0 + q * 4];
        a4[q].x = fmaf(xv[k], wv.x, a4[q].x);
        a4[q].y = fmaf(xv[k], wv.y, a4[q].y);
        a4[q].z = fmaf(xv[k], wv.z, a4[q].z);
        a4[q].w = fmaf(xv[k], wv.w, a4[q].w);
      }
    }
    #pragma unroll
    for (int q = 0; q < 8; ++q) {
      const float4 bb = *(const float4*)&wsmall[6 * HID + c0 + q * 4];
      const int c = c0 + q * 4;
      hT[(c + 0) * MSTR + lane] = fmaxf(a4[q].x + bb.x, 0.f);
      hT[(c + 1) * MSTR + lane] = fmaxf(a4[q].y + bb.y, 0.f);
      hT[(c + 2) * MSTR + lane] = fmaxf(a4[q].z + bb.z, 0.f);
      hT[(c + 3) * MSTR + lane] = fmaxf(a4[q].w + bb.w, 0.f);
    }
  }
  __syncthreads();

  // ---------------- 3 MFMA layers ----------------
  const int mt   = w * 16 + (lane & 15);       // A-frag target row
  const int koct = (lane >> 4) * 8;            // A-frag k-octet base
  const int stt  = s0 - 3 + mt;
  const float invdA = (stt == 0 || stt == SEQ - 1) ? (1.0f / (2.0f + 1e-8f))
                                                   : (1.0f / (3.0f + 1e-8f));
  const int mm = (mt == 0) ? 0 : mt - 1;
  const int mp = (mt == 63) ? 63 : mt + 1;

  #pragma unroll 1
  for (int L = 0; L < 3; ++L) {
    const short* WfL = Wf + L * 32768;
    const bf16x8* Bhi = (const bf16x8*)WfL;
    const bf16x8* Blo = (const bf16x8*)(WfL + 16384);
    const float* bias = (L == 0) ? bp : (L == 1) ? gc2_b : gc3_b;

    f32x4 acc_[8];
    #pragma unroll
    for (int nt = 0; nt < 8; ++nt) acc_[nt] = (f32x4){0.f, 0.f, 0.f, 0.f};

    #pragma unroll 1
    for (int ks = 0; ks < 4; ++ks) {
      // B-frags first (VMEM latency hides behind A assembly)
      const int fb = ks * 512 + lane;
      bf16x8 bh[8], bl[8];
      #pragma unroll
      for (int nt = 0; nt < 8; ++nt) {
        bh[nt] = Bhi[fb + nt * 64];
        bl[nt] = Blo[fb + nt * 64];
      }
      // A-frag: read hT (agg+relu for L>0), cvt_pk pair-split hi/lo
      bf16x8 ah, al;
      {
        const float* pa = &hT[(ks * 32 + koct) * MSTR];
        float v[8];
        #pragma unroll
        for (int j = 0; j < 8; ++j) {
          if (L == 0) {
            v[j] = pa[j * MSTR + mt];
          } else {
            const float t = (pa[j * MSTR + mm] + pa[j * MSTR + mt] +
                             pa[j * MSTR + mp]) * invdA;
            v[j] = fmaxf(t, 0.f);
          }
        }
        u32x4 hv, lv;
        #pragma unroll
        for (int q = 0; q < 4; ++q) {
          const unsigned hp = cvt_pk_bf16(v[2 * q], v[2 * q + 1]);
          const float h0 = __uint_as_float(hp << 16);
          const float h1 = __uint_as_float(hp & 0xffff0000u);
          hv[q] = hp;
          lv[q] = cvt_pk_bf16(v[2 * q] - h0, v[2 * q + 1] - h1);
        }
        ah = __builtin_bit_cast(bf16x8, hv);
        al = __builtin_bit_cast(bf16x8, lv);
      }
      #pragma unroll
      for (int nt = 0; nt < 8; ++nt) {
        acc_[nt] = __builtin_amdgcn_mfma_f32_16x16x32_bf16(ah, bh[nt], acc_[nt], 0, 0, 0);
        acc_[nt] = __builtin_amdgcn_mfma_f32_16x16x32_bf16(ah, bl[nt], acc_[nt], 0, 0, 0);
        acc_[nt] = __builtin_amdgcn_mfma_f32_16x16x32_bf16(al, bh[nt], acc_[nt], 0, 0, 0);
      }
    }
    __syncthreads();   // all hT reads of this layer done

    // epilogue: t = inseq ? acc + bias : 0 -> hT[n][m]  (C/D layout scatter)
    {
      const int n0 = lane & 15;
      const int mrow0 = w * 16 + (lane >> 4) * 4;
      #pragma unroll
      for (int nt = 0; nt < 8; ++nt) {
        const float bn = bias[nt * 16 + n0];
        float* pw = &hT[(nt * 16 + n0) * MSTR];
        #pragma unroll
        for (int r = 0; r < 4; ++r) {
          const int m = mrow0 + r;
          const int s = s0 - 3 + m;
          const bool vld = (s >= 0 && s < SEQ);
          pw[m] = vld ? (acc_[nt][r] + bn) : 0.f;
        }
      }
    }
    __syncthreads();   // publish t for next layer / pool
  }

  // ---------------- pool: h3 = relu(agg(t3)); sum owned rows ----------------
  {
    const int c = tid & 127, half = tid >> 7;
    float ps = 0.f;
    const float* pc = &hT[c * MSTR];
    #pragma unroll 1
    for (int r = 0; r < 29; ++r) {
      const int m = 3 + half * 29 + r;
      const int s = s0 + half * 29 + r;
      if (s < SEQ) {
        const float invd = (s == 0 || s == SEQ - 1) ? (1.0f / (2.0f + 1e-8f))
                                                    : (1.0f / (3.0f + 1e-8f));
        ps += fmaxf((pc[m - 1] + pc[m] + pc[m + 1]) * invd, 0.f);
      }
    }
    psum[tid] = ps;
  }
  __syncthreads();

  // ---------------- publish partial (agent-scope stores, no contention) ----
  if (tid < 128) {
    __hip_atomic_store(&partial[((long long)b * GX + gxb) * HID + tid],
                       psum[tid] + psum[tid + 128],
                       __ATOMIC_RELAXED, __HIP_MEMORY_SCOPE_AGENT);
  }
  // each thread drains its own store acks (coherent point) before barrier
  asm volatile("s_waitcnt vmcnt(0)" ::: "memory");
  __syncthreads();
  if (tid == 0) {
    // RELAXED on purpose — see header comment (no L2 writeback/invalidate).
    const unsigned old = __hip_atomic_fetch_add(&cnt[b], 1u, __ATOMIC_RELAXED,
                                                __HIP_MEMORY_SCOPE_AGENT);
    lastf = (old == GX - 1) ? 1 : 0;
  }
  __syncthreads();
  if (!lastf) return;

  // ---------------- classifier (last block of batch b only) ----------------
  if (tid < 128) {
    float a = 0.f;
    #pragma unroll
    for (int g = 0; g < GX; ++g)
      a += __hip_atomic_load(&partial[((long long)b * GX + g) * HID + tid],
                             __ATOMIC_RELAXED, __HIP_MEMORY_SCOPE_AGENT);
    psum[tid] = a * (1.0f / 2048.0f);
  }
  __syncthreads();
  if (tid < 64) {
    float h = cls_b1[tid];
    for (int k = 0; k < 128; ++k) h = fmaf(psum[k], cls_w1[k * 64 + tid], h);
    psum[128 + tid] = fmaxf(h, 0.f);
  }
  __syncthreads();
  if (tid < 3) {
    float o = cls_b2[tid];
    for (int k = 0; k < 64; ++k) o = fmaf(psum[128 + k], cls_w2[k * 3 + tid], o);
    out[b * 3 + tid] = o;
  }
}

extern "C" void kernel_launch(void* const* d_in, const int* in_sizes, int n_in,
                              void* d_out, int out_size, void* d_ws, size_t ws_size,
                              hipStream_t stream) {
  (void)in_sizes; (void)n_in; (void)out_size; (void)ws_size;
  const float* x      = (const float*)d_in[0];
  const float* enc_w1 = (const float*)d_in[1];
  const float* enc_b1 = (const float*)d_in[2];
  const float* enc_w2 = (const float*)d_in[3];
  const float* enc_b2 = (const float*)d_in[4];
  const float* gc1_w  = (const float*)d_in[5];
  const float* gc1_b  = (const float*)d_in[6];
  const float* gc2_w  = (const float*)d_in[7];
  const float* gc2_b  = (const float*)d_in[8];
  const float* gc3_w  = (const float*)d_in[9];
  const float* gc3_b  = (const float*)d_in[10];
  const float* cls_w1 = (const float*)d_in[11];
  const float* cls_b1 = (const float*)d_in[12];
  const float* cls_w2 = (const float*)d_in[13];
  const float* cls_b2 = (const float*)d_in[14];

  // workspace layout (rewritten fully every launch — ws is re-poisoned)
  float* bpv     = (float*)d_ws;                     // 128 f32
  short* Wfrag   = (short*)(bpv + 128);              // 3 * 2 * 16384 bf16
  float* partial = (float*)(Wfrag + 3 * 2 * 16384);  // NB*GX*HID f32 (all slots rewritten)
  unsigned* cntb = (unsigned*)(partial + (long long)NB * GX * HID);  // NB u32 (zeroed by prep)

  prep_kernel<<<dim3(97), 256, 0, stream>>>(enc_w2, enc_b2, gc1_w, gc1_b,
                                            gc2_w, gc3_w, Wfrag, bpv, cntb);
  fused_kernel<<<dim3(GX, NB), 256, 0, stream>>>(
      x, enc_w1, enc_b1, Wfrag, bpv, gc2_b, gc3_b, partial, cntb,
      cls_w1, cls_b1, cls_w2, cls_b2, (float*)d_out);
}